// Round 4
// baseline (22854.636 us; speedup 1.0000x reference)
//
#include <hip/hip_runtime.h>
#include <stdint.h>

typedef unsigned int u32;
typedef unsigned long long u64;

#define NBLK 256
#define NTHR 1024
#define Bz 4
#define Tz 128
#define Hz 1024
#define Ez 512
#define Az 512
#define Vz 16000
#define NSTEPS 512
#define XS 1032   // LDS row stride (floats); 1032*4 bytes is 16B-aligned, 8-bank shift/row

#define AVFLAG 384   // u32 idx: av ready, 128 producers/step
#define SCRFLAG 448  // u32 idx: scores ready, 64 producers/step

// ---------------- ws layout (bytes) ----------------
// [0,      8192)   ctrl u32s: grp[g] @ g*16 (g<16), root @ 256, gen @ 320,
//                  avflag @ 384, scrflag @ 448
// [8192,   10240)  score_g[4][128] f32
// [16384,  49152)  h_g[2][4][1024] f32  (double-buffered)
// [49152,  57344)  av_g[4][512] f32
// [57344,  65536)  amax_g[256][4] u64
// [65536,  +2MB )  encout[4][128][1024] f32
// then             pt[4][512][128] f32

__device__ __forceinline__ float sigf(float x) { return 1.0f / (1.0f + expf(-x)); }

// interleaved k-split dot: lane owns float4 chunks {lane + L*k : k<K}
template <int K, int L>
__device__ __forceinline__ float idot(const float4* __restrict__ w4,
                                      const float4* __restrict__ v4, int lane) {
  float4 acc = make_float4(0.f, 0.f, 0.f, 0.f);
#pragma unroll 8
  for (int k = 0; k < K; ++k) {
    float4 a = w4[lane + L * k];
    float4 b = v4[lane + L * k];
    acc.x += a.x * b.x; acc.y += a.y * b.y; acc.z += a.z * b.z; acc.w += a.w * b.w;
  }
  return (acc.x + acc.y) + (acc.z + acc.w);
}

// two-level grid barrier, monotonic epochs; arrive/wait split so non-consumer
// blocks can skip the poll. Polls RELAXED + one ACQUIRE on exit.
__device__ __forceinline__ void bar_arrive(u32* ctrl, int epoch) {
  __syncthreads();
  if (threadIdx.x == 0) {
    const u32 target = (u32)epoch * 16u;
    u32* grp = ctrl + ((blockIdx.x >> 4) * 16);
    u32 v = __hip_atomic_fetch_add(grp, 1u, __ATOMIC_RELEASE, __HIP_MEMORY_SCOPE_AGENT);
    if (v == target - 1u) {
      u32 r = __hip_atomic_fetch_add(ctrl + 256, 1u, __ATOMIC_ACQ_REL, __HIP_MEMORY_SCOPE_AGENT);
      if (r == target - 1u)
        __hip_atomic_store(ctrl + 320, (u32)epoch, __ATOMIC_RELEASE, __HIP_MEMORY_SCOPE_AGENT);
    }
  }
}

__device__ __forceinline__ void bar_wait(u32* ctrl, int epoch) {
  if (threadIdx.x == 0) {
    while (__hip_atomic_load(ctrl + 320, __ATOMIC_RELAXED, __HIP_MEMORY_SCOPE_AGENT) < (u32)epoch)
      __builtin_amdgcn_s_sleep(4);
    (void)__hip_atomic_load(ctrl + 320, __ATOMIC_ACQUIRE, __HIP_MEMORY_SCOPE_AGENT);
  }
  __syncthreads();
}

__device__ __forceinline__ void flag_inc(u32* ctrl, int idx) {
  __syncthreads();  // drain this block's stores before release
  if (threadIdx.x == 0)
    __hip_atomic_fetch_add(ctrl + idx, 1u, __ATOMIC_RELEASE, __HIP_MEMORY_SCOPE_AGENT);
}

__device__ __forceinline__ void flag_wait(u32* ctrl, int idx, u32 tgt) {
  if (threadIdx.x == 0) {
    while (__hip_atomic_load(ctrl + idx, __ATOMIC_RELAXED, __HIP_MEMORY_SCOPE_AGENT) < tgt)
      __builtin_amdgcn_s_sleep(4);
    (void)__hip_atomic_load(ctrl + idx, __ATOMIC_ACQUIRE, __HIP_MEMORY_SCOPE_AGENT);
  }
  __syncthreads();
}

__global__ void __launch_bounds__(NTHR, 1) seq2seq_kernel(
    const int* __restrict__ inputs,
    const float* __restrict__ enc_emb, const float* __restrict__ enc_Wih,
    const float* __restrict__ enc_Whh, const float* __restrict__ enc_bih,
    const float* __restrict__ enc_bhh,
    const float* __restrict__ dec_emb, const float* __restrict__ dec_Wih,
    const float* __restrict__ dec_Whh, const float* __restrict__ dec_bih,
    const float* __restrict__ dec_bhh,
    const float* __restrict__ W_av, const float* __restrict__ b_av,
    const float* __restrict__ W_cls, const float* __restrict__ b_cls,
    float* __restrict__ out, char* __restrict__ ws) {
  const int tid = threadIdx.x;
  const int bid = blockIdx.x;

  u32* ctrl = (u32*)ws;
  float* score_g = (float*)(ws + 8192);  // [4][128]
  float* h_g = (float*)(ws + 16384);     // [2][4][1024]
  float* av_g = (float*)(ws + 49152);    // [4][512]
  u64* amax_g = (u64*)(ws + 57344);      // [256][4]
  float* encout_g = (float*)(ws + 65536);
  float* pt_g = encout_g + Bz * Tz * Hz;
  float* out_pred = out;                        // [512][4][16000]
  float* out_aw = out + (long)NSTEPS * Bz * Vz; // [512][4][128]

  // GRU weights LDS-resident: rows 0..11 = W_ih, 12..23 = W_hh. ~96.75 KB.
  __shared__ __align__(16) float wlds[24][XS];
  __shared__ __align__(16) float x_s[Bz][XS];
  __shared__ __align__(16) float h_s[Bz][XS];
  __shared__ __align__(16) float at_s[Bz][516];
  __shared__ __align__(16) float hb_s[XS];
  __shared__ __align__(16) float e1_s[132];
  __shared__ float qh_s[16];
  __shared__ float g_s[Bz][6][4];
  __shared__ float sinv_s;
  __shared__ int ids_s[Bz];
  __shared__ u64 am_s[Bz][64];

  int epoch = 0;
  const int jbase = bid * 4;         // this block's 4 hidden dims
  const int t8 = tid >> 3, l8 = tid & 7;
  // GRU task map (t8<96), b-uniform per wave
  const int b8 = t8 / 24;
  const int r6 = t8 % 24;
  const int g6 = r6 >> 2, jl = r6 & 3;
  const int lrow = r6;  // wlds row (== r6 for both ih and hh halves)
  const int grow = ((g6 < 3) ? g6 : g6 - 3) * Hz + jbase + jl;

  // ---- stage ENCODER GRU weights into LDS (once) ----
  for (int idx = tid; idx < 12 * Ez; idx += NTHR) {
    int lr = idx >> 9, c = idx & 511;
    wlds[lr][c] = enc_Wih[(long)((lr >> 2) * Hz + jbase + (lr & 3)) * Ez + c];
  }
  for (int idx = tid; idx < 12 * Hz; idx += NTHR) {
    int lr = idx >> 10, c = idx & 1023;
    wlds[12 + lr][c] = enc_Whh[(long)((lr >> 2) * Hz + jbase + (lr & 3)) * Hz + c];
  }
  float gbias = 0.f;
  if (t8 < 96) gbias = (g6 < 3) ? enc_bih[grow] : enc_bhh[grow];
  __syncthreads();

  // ================= encoder: 128 GRU steps =================
  for (int t = 0; t < Tz; ++t) {
    float* hrd = h_g + (t & 1) * (Bz * Hz);
    float* hwr = h_g + ((t + 1) & 1) * (Bz * Hz);
    for (int idx = tid; idx < Bz * Ez; idx += NTHR) {
      int b = idx >> 9, k = idx & 511;
      x_s[b][k] = enc_emb[(long)inputs[b * Tz + t] * Ez + k];
    }
    for (int idx = tid; idx < Bz * Hz; idx += NTHR)
      h_s[idx >> 10][idx & 1023] = hrd[idx];
    __syncthreads();
    if (t8 < 96) {
      const float4* w4 = (const float4*)&wlds[lrow][0];
      float acc;
      if (g6 < 3) acc = idot<16, 8>(w4, (const float4*)&x_s[b8][0], l8);
      else        acc = idot<32, 8>(w4, (const float4*)&h_s[b8][0], l8);
      acc += __shfl_xor(acc, 1); acc += __shfl_xor(acc, 2); acc += __shfl_xor(acc, 4);
      if (l8 == 0) g_s[b8][g6][jl] = acc + gbias;
    }
    __syncthreads();
    if (tid < 16) {
      int b = tid & 3, jj = tid >> 2;
      int j = jbase + jj;
      float r = sigf(g_s[b][0][jj] + g_s[b][3][jj]);
      float z = sigf(g_s[b][1][jj] + g_s[b][4][jj]);
      float n = tanhf(g_s[b][2][jj] + r * g_s[b][5][jj]);
      float hv = (1.0f - z) * n + z * h_s[b][j];
      hwr[b * Hz + j] = hv;
      encout_g[((long)(b * Tz) + t) * Hz + j] = hv;
    }
    ++epoch; bar_arrive(ctrl, epoch); bar_wait(ctrl, epoch);
  }

  // ================= P_t = enc_outs @ W_av_ctx^T (one-time) =================
  {
    int a = (bid >> 2) * 8 + (tid >> 7);
    int bt = (bid & 3) * 128 + (tid & 127);
    int b = bt >> 7, t2 = bt & 127;
    float acc = idot<256, 1>((const float4*)(W_av + (long)a * (2 * Hz)),
                             (const float4*)(encout_g + (long)bt * Hz), 0);
    pt_g[((long)(b * Az) + a) * Tz + t2] = acc;
    ++epoch; bar_arrive(ctrl, epoch); bar_wait(ctrl, epoch);
  }

  // ---- swap LDS weights: encoder -> decoder GRU ----
  for (int idx = tid; idx < 12 * Hz; idx += NTHR) {
    int lr = idx >> 10, c = idx & 1023;
    long gr = (long)((lr >> 2) * Hz + jbase + (lr & 3));
    wlds[lr][c] = dec_Wih[gr * 1024 + c];
    wlds[12 + lr][c] = dec_Whh[gr * Hz + c];
  }
  if (t8 < 96) gbias = (g6 < 3) ? dec_bih[grow] : dec_bhh[grow];

  // ============ W_cls pinned in registers for the whole decoder ============
  const int task16 = tid >> 4, l16 = tid & 15;
  const int nrows = 62 + (bid < 128 ? 1 : 0);
  const int rbase = bid * 62 + (bid < 128 ? bid : 128);
  const int myrow = rbase + (task16 < nrows ? task16 : 0);
  float4 wreg[8];
  {
    const float4* wr4 = (const float4*)(W_cls + (long)myrow * Az);
#pragma unroll
    for (int k = 0; k < 8; ++k) wreg[k] = wr4[l16 + 16 * k];
  }
  const float bclsr = b_cls[myrow];

  // ---- A-phase roles ----
  // ctx blocks 0..127: (b = bid>>5, a-chunk of 16 @ ca); compute qh+softmax+ctx+av
  // scr blocks 128..191: (b = (bid-128)>>4, t-chunk of 8 @ st); compute scores
  const bool is_ctx = bid < 128;
  const bool is_scr = (bid >= 128) && (bid < 192);
  const int cb = bid >> 5, ca = (bid & 31) * 16;
  const int sgw = bid - 128;
  const int sb = sgw >> 4, st = (sgw & 15) * 8;
  const int wv = tid >> 6, lane = tid & 63;
  __syncthreads();                    // wlds swap complete before first decoder step

  // ================= decoder: 512 greedy steps =================
  for (int s = 0; s < NSTEPS; ++s) {
    float* hrd = h_g + (s & 1) * (Bz * Hz);
    float* hwr = h_g + ((s & 1) ^ 1) * (Bz * Hz);

    // ---- P1: argmax finalize -> ids, stage x/h, GRU (all 256 blocks) ----
    if (tid < 256) {
      int b = tid >> 6, l = tid & 63;
      u64 best = 0;
#pragma unroll
      for (int g = 0; g < 4; ++g) {
        u64 v = amax_g[(l + 64 * g) * 4 + b];
        best = v > best ? v : best;
      }
      for (int off = 32; off; off >>= 1) {
        u64 o = __shfl_xor(best, off);
        best = o > best ? o : best;
      }
      if (l == 0) ids_s[b] = (int)(0xFFFFFFFFu - (u32)(best & 0xFFFFFFFFull));
    }
    __syncthreads();
    for (int idx = tid; idx < Bz * (Ez + Az); idx += NTHR) {
      int b = idx >> 10, k = idx & 1023;
      x_s[b][k] = (k < Ez) ? dec_emb[(long)ids_s[b] * Ez + k] : av_g[b * Az + (k - Ez)];
    }
    for (int idx = tid; idx < Bz * Hz; idx += NTHR)
      h_s[idx >> 10][idx & 1023] = hrd[idx];
    __syncthreads();
    if (t8 < 96) {
      const float4* w4 = (const float4*)&wlds[lrow][0];
      const float4* v4 = (const float4*)((g6 < 3) ? &x_s[b8][0] : &h_s[b8][0]);
      float acc = idot<32, 8>(w4, v4, l8);
      acc += __shfl_xor(acc, 1); acc += __shfl_xor(acc, 2); acc += __shfl_xor(acc, 4);
      if (l8 == 0) g_s[b8][g6][jl] = acc + gbias;
    }
    __syncthreads();
    if (tid < 16) {
      int b = tid & 3, jj = tid >> 2;
      int j = jbase + jj;
      float r = sigf(g_s[b][0][jj] + g_s[b][3][jj]);
      float z = sigf(g_s[b][1][jj] + g_s[b][4][jj]);
      float n = tanhf(g_s[b][2][jj] + r * g_s[b][5][jj]);
      hwr[b * Hz + j] = (1.0f - z) * n + z * h_s[b][j];
    }
    ++epoch;
    bar_arrive(ctrl, epoch);   // h-ready: all arrive...

    // ---- A-phase: scores (64 blks) || qh+softmax+ctx+av (128 blks) ----
    if (is_scr) {
      bar_wait(ctrl, epoch);
      for (int idx = tid; idx < Hz; idx += NTHR) hb_s[idx] = hwr[sb * Hz + idx];
      __syncthreads();
      if (wv < 8) {        // 8 tasks x 64 lanes: score dots
        int t = st + wv;
        float acc = idot<4, 64>((const float4*)(encout_g + ((long)(sb * Tz) + t) * Hz),
                                (const float4*)hb_s, lane);
#pragma unroll
        for (int off = 32; off; off >>= 1) acc += __shfl_xor(acc, off);
        if (lane == 0)
          score_g[sb * Tz + t] = (inputs[sb * Tz + t] != 0) ? acc : -1e30f;
      }
      flag_inc(ctrl, SCRFLAG);
    } else if (is_ctx) {
      bar_wait(ctrl, epoch);
      for (int idx = tid; idx < Hz; idx += NTHR) hb_s[idx] = hwr[cb * Hz + idx];
      __syncthreads();
      {                    // 16 tasks x 64 lanes: qh dots (block-private W_av slice)
        int a = ca + wv;
        float qa = idot<4, 64>((const float4*)(W_av + (long)a * (2 * Hz) + Hz),
                               (const float4*)hb_s, lane);
#pragma unroll
        for (int off = 32; off; off >>= 1) qa += __shfl_xor(qa, off);
        if (lane == 0) qh_s[wv] = qa;
      }
      flag_wait(ctrl, SCRFLAG, (u32)(64 * (s + 1)));
      if (tid < 64) {      // softmax over 128 (redundant per ctx block)
        float s0 = score_g[cb * Tz + tid], s1 = score_g[cb * Tz + 64 + tid];
        float m = fmaxf(s0, s1);
#pragma unroll
        for (int off = 32; off; off >>= 1) m = fmaxf(m, __shfl_xor(m, off));
        float e0 = expf(s0 - m), e1 = expf(s1 - m);
        float sum = e0 + e1;
#pragma unroll
        for (int off = 32; off; off >>= 1) sum += __shfl_xor(sum, off);
        e1_s[tid] = e0; e1_s[64 + tid] = e1;
        if (tid == 0) sinv_s = 1.0f / sum;
      }
      __syncthreads();
      if (tid < 128) {     // 16 tasks x 8 lanes: context dots over t
        int task = tid >> 3, a = ca + task;
        float ctx = idot<4, 8>((const float4*)(pt_g + ((long)(cb * Az) + a) * Tz),
                               (const float4*)e1_s, l8);
        ctx += __shfl_xor(ctx, 1); ctx += __shfl_xor(ctx, 2); ctx += __shfl_xor(ctx, 4);
        if (l8 == 0)
          av_g[cb * Az + a] = tanhf(ctx * sinv_s + qh_s[task] + b_av[a]);
      }
      if (ca == 0 && tid < 128)  // a-chunk-0 block per b emits attention weights
        out_aw[(long)s * (Bz * Tz) + cb * Tz + tid] = e1_s[tid] * sinv_s;
      flag_inc(ctrl, AVFLAG);
    }

    // ---- all blocks: wait for av ready (128 producers) ----
    flag_wait(ctrl, AVFLAG, (u32)(128 * (s + 1)));

    // ---- P3: logits from register-resident W_cls + block-local argmax ----
    for (int idx = tid; idx < Bz * Az; idx += NTHR)
      at_s[idx >> 9][idx & 511] = av_g[idx];
    __syncthreads();
#pragma unroll
    for (int b = 0; b < 4; ++b) {
      const float4* a4 = (const float4*)&at_s[b][0];
      float acc = 0.f;
#pragma unroll
      for (int k = 0; k < 8; ++k) {
        float4 a = a4[l16 + 16 * k];
        acc += wreg[k].x * a.x + wreg[k].y * a.y + wreg[k].z * a.z + wreg[k].w * a.w;
      }
      acc += __shfl_xor(acc, 1); acc += __shfl_xor(acc, 2);
      acc += __shfl_xor(acc, 4); acc += __shfl_xor(acc, 8);
      if (l16 == 0 && task16 < nrows) {
        acc += bclsr;
        out_pred[((long)s * Bz + b) * Vz + myrow] = acc;
        u32 u = __float_as_uint(acc);
        u = (u & 0x80000000u) ? ~u : (u | 0x80000000u);
        am_s[b][task16] = ((u64)u << 32) | (u64)(0xFFFFFFFFu - (u32)myrow);
      }
    }
    __syncthreads();
    if (tid < 256) {
      int b2 = tid >> 6, l = tid & 63;
      u64 best = (l < nrows) ? am_s[b2][l] : 0ull;
      for (int off = 32; off; off >>= 1) {
        u64 o = __shfl_xor(best, off);
        best = o > best ? o : best;
      }
      if (l == 0) amax_g[bid * 4 + b2] = best;
    }
    ++epoch;
    bar_arrive(ctrl, epoch);  // step-end: full barrier (argmax partials)
    bar_wait(ctrl, epoch);
  }
}

extern "C" void kernel_launch(void* const* d_in, const int* in_sizes, int n_in,
                              void* d_out, int out_size, void* d_ws, size_t ws_size,
                              hipStream_t stream) {
  const int* inputs = (const int*)d_in[0];
  const float* enc_emb = (const float*)d_in[1];
  const float* enc_Wih = (const float*)d_in[2];
  const float* enc_Whh = (const float*)d_in[3];
  const float* enc_bih = (const float*)d_in[4];
  const float* enc_bhh = (const float*)d_in[5];
  const float* dec_emb = (const float*)d_in[6];
  const float* dec_Wih = (const float*)d_in[7];
  const float* dec_Whh = (const float*)d_in[8];
  const float* dec_bih = (const float*)d_in[9];
  const float* dec_bhh = (const float*)d_in[10];
  const float* W_av = (const float*)d_in[11];
  const float* b_av = (const float*)d_in[12];
  const float* W_cls = (const float*)d_in[13];
  const float* b_cls = (const float*)d_in[14];

  // zero barrier state + score + h (both buffers) + attn_vec; 0xFF argmax
  // partials so step-0 ids decode to 0
  hipMemsetAsync(d_ws, 0, 57344, stream);
  hipMemsetAsync((char*)d_ws + 57344, 0xFF, 8192, stream);

  seq2seq_kernel<<<dim3(NBLK), dim3(NTHR), 0, stream>>>(
      inputs, enc_emb, enc_Wih, enc_Whh, enc_bih, enc_bhh,
      dec_emb, dec_Wih, dec_Whh, dec_bih, dec_bhh,
      W_av, b_av, W_cls, b_cls,
      (float*)d_out, (char*)d_ws);
}

// Round 5
// 20752.501 us; speedup vs baseline: 1.1013x; 1.1013x over previous
//
#include <hip/hip_runtime.h>
#include <stdint.h>

typedef unsigned int u32;
typedef unsigned long long u64;

#define NBLK 256
#define NTHR 1024
#define Bz 4
#define Tz 128
#define Hz 1024
#define Ez 512
#define Az 512
#define Vz 16000
#define NSTEPS 512
#define XS 1032   // LDS row stride (floats); 1032*4 bytes is 16B-aligned, 8-bank shift/row

// ---------------- ws layout (bytes) ----------------
// [0,      8192)   ctrl u32s for one-time classic bar: grp[g]@g*16, root@256, gen@320
// [8192,   9216)   hseq[256] u32   (enc step t writes t+1; dec step s writes 129+s)
// [9216,   10240)  avseq[16] u32   (dec step s: ctx block bid<16 writes s+1)
// [10240,  11264)  amseq[256] u32  (dec step s: every block writes s+1 after amax)
// [16384,  49152)  h_g[2][4][1024] f32  (double-buffered)
// [49152,  57344)  av_g[4][512] f32
// [57344,  65536)  amax_g[256][4] u64
// [65536,  +2MB )  encout[4][128][1024] f32
// then             pt[4][512][128] f32

__device__ __forceinline__ float sigf(float x) { return 1.0f / (1.0f + expf(-x)); }

__device__ __forceinline__ u32 ld_rlx(const u32* p) {
  return __hip_atomic_load(p, __ATOMIC_RELAXED, __HIP_MEMORY_SCOPE_AGENT);
}
__device__ __forceinline__ void st_rel(u32* p, u32 v) {
  __hip_atomic_store(p, v, __ATOMIC_RELEASE, __HIP_MEMORY_SCOPE_AGENT);
}

// wave0 polls a 256-slot seq array until ALL >= tgt; one acquire; block barrier.
__device__ __forceinline__ void poll256(const u32* sq, u32 tgt) {
  if (threadIdx.x < 64) {
    const int l = threadIdx.x;
    while (true) {
      u32 m0 = ld_rlx(sq + l);
      u32 m1 = ld_rlx(sq + l + 64);
      u32 m2 = ld_rlx(sq + l + 128);
      u32 m3 = ld_rlx(sq + l + 192);
      u32 a = m0 < m1 ? m0 : m1;
      u32 b = m2 < m3 ? m2 : m3;
      u32 mn = a < b ? a : b;
      if (__all(mn >= tgt)) break;
      __builtin_amdgcn_s_sleep(2);
    }
    if (l == 0)
      (void)__hip_atomic_load(sq, __ATOMIC_ACQUIRE, __HIP_MEMORY_SCOPE_AGENT);
  }
  __syncthreads();
}

// wave0 polls a 16-slot seq array until ALL >= tgt; one acquire; block barrier.
__device__ __forceinline__ void poll16(const u32* sq, u32 tgt) {
  if (threadIdx.x < 64) {
    while (true) {
      u32 v = (threadIdx.x < 16) ? ld_rlx(sq + threadIdx.x) : 0xFFFFFFFFu;
      if (__all(v >= tgt)) break;
      __builtin_amdgcn_s_sleep(2);
    }
    if (threadIdx.x == 0)
      (void)__hip_atomic_load(sq, __ATOMIC_ACQUIRE, __HIP_MEMORY_SCOPE_AGENT);
  }
  __syncthreads();
}

// interleaved k-split dot: lane owns float4 chunks {lane + L*k : k<K}
template <int K, int L>
__device__ __forceinline__ float idot(const float4* __restrict__ w4,
                                      const float4* __restrict__ v4, int lane) {
  float4 acc = make_float4(0.f, 0.f, 0.f, 0.f);
#pragma unroll 8
  for (int k = 0; k < K; ++k) {
    float4 a = w4[lane + L * k];
    float4 b = v4[lane + L * k];
    acc.x += a.x * b.x; acc.y += a.y * b.y; acc.z += a.z * b.z; acc.w += a.w * b.w;
  }
  return (acc.x + acc.y) + (acc.z + acc.w);
}

// classic two-level grid barrier — used ONCE (after P_t).
__device__ __forceinline__ void bar_arrive(u32* ctrl, int epoch) {
  __syncthreads();
  if (threadIdx.x == 0) {
    const u32 target = (u32)epoch * 16u;
    u32* grp = ctrl + ((blockIdx.x >> 4) * 16);
    u32 v = __hip_atomic_fetch_add(grp, 1u, __ATOMIC_RELEASE, __HIP_MEMORY_SCOPE_AGENT);
    if (v == target - 1u) {
      u32 r = __hip_atomic_fetch_add(ctrl + 256, 1u, __ATOMIC_ACQ_REL, __HIP_MEMORY_SCOPE_AGENT);
      if (r == target - 1u)
        __hip_atomic_store(ctrl + 320, (u32)epoch, __ATOMIC_RELEASE, __HIP_MEMORY_SCOPE_AGENT);
    }
  }
}

__device__ __forceinline__ void bar_wait(u32* ctrl, int epoch) {
  if (threadIdx.x == 0) {
    while (__hip_atomic_load(ctrl + 320, __ATOMIC_RELAXED, __HIP_MEMORY_SCOPE_AGENT) < (u32)epoch)
      __builtin_amdgcn_s_sleep(4);
    (void)__hip_atomic_load(ctrl + 320, __ATOMIC_ACQUIRE, __HIP_MEMORY_SCOPE_AGENT);
  }
  __syncthreads();
}

__global__ void __launch_bounds__(NTHR, 1) seq2seq_kernel(
    const int* __restrict__ inputs,
    const float* __restrict__ enc_emb, const float* __restrict__ enc_Wih,
    const float* __restrict__ enc_Whh, const float* __restrict__ enc_bih,
    const float* __restrict__ enc_bhh,
    const float* __restrict__ dec_emb, const float* __restrict__ dec_Wih,
    const float* __restrict__ dec_Whh, const float* __restrict__ dec_bih,
    const float* __restrict__ dec_bhh,
    const float* __restrict__ W_av, const float* __restrict__ b_av,
    const float* __restrict__ W_cls, const float* __restrict__ b_cls,
    float* __restrict__ out, char* __restrict__ ws) {
  const int tid = threadIdx.x;
  const int bid = blockIdx.x;

  u32* ctrl = (u32*)ws;
  u32* hseq = (u32*)(ws + 8192);   // [256]
  u32* avseq = (u32*)(ws + 9216);  // [16]
  u32* amseq = (u32*)(ws + 10240); // [256]
  float* h_g = (float*)(ws + 16384);     // [2][4][1024]
  float* av_g = (float*)(ws + 49152);    // [4][512]
  u64* amax_g = (u64*)(ws + 57344);      // [256][4]
  float* encout_g = (float*)(ws + 65536);
  float* pt_g = encout_g + Bz * Tz * Hz;
  float* out_pred = out;                        // [512][4][16000]
  float* out_aw = out + (long)NSTEPS * Bz * Vz; // [512][4][128]

  // GRU weights LDS-resident: rows 0..11 = W_ih, 12..23 = W_hh. ~96.75 KB.
  __shared__ __align__(16) float wlds[24][XS];
  __shared__ __align__(16) float x_s[Bz][XS];
  __shared__ __align__(16) float h_s[Bz][XS];
  __shared__ __align__(16) float at_s[Bz][516];
  __shared__ __align__(16) float hb_s[XS];
  __shared__ __align__(16) float e1_s[132];
  __shared__ float sc_s[128];
  __shared__ float qh_s[128];
  __shared__ float g_s[Bz][6][4];
  __shared__ float sinv_s;
  __shared__ int ids_s[Bz];
  __shared__ u64 am_s[Bz][64];

  const int jbase = bid * 4;         // this block's 4 hidden dims
  const int t8 = tid >> 3, l8 = tid & 7;
  // GRU task map (t8<96), b-uniform per wave
  const int b8 = t8 / 24;
  const int r6 = t8 % 24;
  const int g6 = r6 >> 2, jl = r6 & 3;
  const int lrow = r6;
  const int grow = ((g6 < 3) ? g6 : g6 - 3) * Hz + jbase + jl;

  // ---- stage ENCODER GRU weights into LDS (once) ----
  for (int idx = tid; idx < 12 * Ez; idx += NTHR) {
    int lr = idx >> 9, c = idx & 511;
    wlds[lr][c] = enc_Wih[(long)((lr >> 2) * Hz + jbase + (lr & 3)) * Ez + c];
  }
  for (int idx = tid; idx < 12 * Hz; idx += NTHR) {
    int lr = idx >> 10, c = idx & 1023;
    wlds[12 + lr][c] = enc_Whh[(long)((lr >> 2) * Hz + jbase + (lr & 3)) * Hz + c];
  }
  float gbias = 0.f;
  if (t8 < 96) gbias = (g6 < 3) ? enc_bih[grow] : enc_bhh[grow];
  __syncthreads();

  // ================= encoder: 128 GRU steps (slot-synced, no barriers) =====
  for (int t = 0; t < Tz; ++t) {
    poll256(hseq, (u32)t);           // all blocks finished step t-1
    float* hrd = h_g + (t & 1) * (Bz * Hz);
    float* hwr = h_g + ((t + 1) & 1) * (Bz * Hz);
    for (int idx = tid; idx < Bz * Ez; idx += NTHR) {
      int b = idx >> 9, k = idx & 511;
      x_s[b][k] = enc_emb[(long)inputs[b * Tz + t] * Ez + k];
    }
    for (int idx = tid; idx < Bz * Hz; idx += NTHR)
      h_s[idx >> 10][idx & 1023] = hrd[idx];
    __syncthreads();
    if (t8 < 96) {
      const float4* w4 = (const float4*)&wlds[lrow][0];
      float acc;
      if (g6 < 3) acc = idot<16, 8>(w4, (const float4*)&x_s[b8][0], l8);
      else        acc = idot<32, 8>(w4, (const float4*)&h_s[b8][0], l8);
      acc += __shfl_xor(acc, 1); acc += __shfl_xor(acc, 2); acc += __shfl_xor(acc, 4);
      if (l8 == 0) g_s[b8][g6][jl] = acc + gbias;
    }
    __syncthreads();
    if (tid < 16) {
      int b = tid & 3, jj = tid >> 2;
      int j = jbase + jj;
      float r = sigf(g_s[b][0][jj] + g_s[b][3][jj]);
      float z = sigf(g_s[b][1][jj] + g_s[b][4][jj]);
      float n = tanhf(g_s[b][2][jj] + r * g_s[b][5][jj]);
      float hv = (1.0f - z) * n + z * h_s[b][j];
      hwr[b * Hz + j] = hv;
      encout_g[((long)(b * Tz) + t) * Hz + j] = hv;
    }
    __syncthreads();
    if (tid == 0) st_rel(hseq + bid, (u32)(t + 1));
  }

  // ================= P_t = enc_outs @ W_av_ctx^T (one-time) =================
  poll256(hseq, (u32)Tz);            // all encoder h/encout published
  {
    int a = (bid >> 2) * 8 + (tid >> 7);
    int bt = (bid & 3) * 128 + (tid & 127);
    int b = bt >> 7, t2 = bt & 127;
    float acc = idot<256, 1>((const float4*)(W_av + (long)a * (2 * Hz)),
                             (const float4*)(encout_g + (long)bt * Hz), 0);
    pt_g[((long)(b * Az) + a) * Tz + t2] = acc;
  }
  bar_arrive(ctrl, 1); bar_wait(ctrl, 1);   // one-time classic barrier

  // ---- swap LDS weights: encoder -> decoder GRU ----
  for (int idx = tid; idx < 12 * Hz; idx += NTHR) {
    int lr = idx >> 10, c = idx & 1023;
    long gr = (long)((lr >> 2) * Hz + jbase + (lr & 3));
    wlds[lr][c] = dec_Wih[gr * 1024 + c];
    wlds[12 + lr][c] = dec_Whh[gr * Hz + c];
  }
  if (t8 < 96) gbias = (g6 < 3) ? dec_bih[grow] : dec_bhh[grow];

  // ============ W_cls pinned in registers for the whole decoder ============
  const int task16 = tid >> 4, l16 = tid & 15;
  const int nrows = 62 + (bid < 128 ? 1 : 0);
  const int rbase = bid * 62 + (bid < 128 ? bid : 128);
  const int myrow = rbase + (task16 < nrows ? task16 : 0);
  float4 wreg[8];
  {
    const float4* wr4 = (const float4*)(W_cls + (long)myrow * Az);
#pragma unroll
    for (int k = 0; k < 8; ++k) wreg[k] = wr4[l16 + 16 * k];
  }
  const float bclsr = b_cls[myrow];

  const int atn_b = bid & 3;          // attn block: batch
  const int abase = (bid >> 2) * 128; // attn block: a-slice base
  __syncthreads();                    // wlds swap complete before first decoder step

  // ================= decoder: 512 greedy steps =================
  for (int s = 0; s < NSTEPS; ++s) {
    float* hrd = h_g + (s & 1) * (Bz * Hz);
    float* hwr = h_g + ((s & 1) ^ 1) * (Bz * Hz);

    // ---- P1: wait prev-step amax (data-carrying barrier), ids, GRU ----
    poll256(amseq, (u32)s);          // all blocks' P3(s-1) published
    if (tid < 256) {
      int b = tid >> 6, l = tid & 63;
      u64 best = 0;
#pragma unroll
      for (int g = 0; g < 4; ++g) {
        u64 v = amax_g[(l + 64 * g) * 4 + b];
        best = v > best ? v : best;
      }
      for (int off = 32; off; off >>= 1) {
        u64 o = __shfl_xor(best, off);
        best = o > best ? o : best;
      }
      if (l == 0) ids_s[b] = (int)(0xFFFFFFFFu - (u32)(best & 0xFFFFFFFFull));
    }
    __syncthreads();
    for (int idx = tid; idx < Bz * (Ez + Az); idx += NTHR) {
      int b = idx >> 10, k = idx & 1023;
      x_s[b][k] = (k < Ez) ? dec_emb[(long)ids_s[b] * Ez + k] : av_g[b * Az + (k - Ez)];
    }
    for (int idx = tid; idx < Bz * Hz; idx += NTHR)
      h_s[idx >> 10][idx & 1023] = hrd[idx];
    __syncthreads();
    if (t8 < 96) {
      const float4* w4 = (const float4*)&wlds[lrow][0];
      const float4* v4 = (const float4*)((g6 < 3) ? &x_s[b8][0] : &h_s[b8][0]);
      float acc = idot<32, 8>(w4, v4, l8);
      acc += __shfl_xor(acc, 1); acc += __shfl_xor(acc, 2); acc += __shfl_xor(acc, 4);
      if (l8 == 0) g_s[b8][g6][jl] = acc + gbias;
    }
    __syncthreads();
    if (tid < 16) {
      int b = tid & 3, jj = tid >> 2;
      int j = jbase + jj;
      float r = sigf(g_s[b][0][jj] + g_s[b][3][jj]);
      float z = sigf(g_s[b][1][jj] + g_s[b][4][jj]);
      float n = tanhf(g_s[b][2][jj] + r * g_s[b][5][jj]);
      hwr[b * Hz + j] = (1.0f - z) * n + z * h_s[b][j];
    }
    __syncthreads();
    if (tid == 0) st_rel(hseq + bid, (u32)(Tz + 1 + s));   // h(s) published

    // ---- P2: fused scores+softmax+qh+attn_vec, blocks 0..15 only ----
    if (bid < 16) {
      poll256(hseq, (u32)(Tz + 1 + s));   // only attn blocks wait on h
      const int b = atn_b;
      for (int idx = tid; idx < Hz; idx += NTHR) hb_s[idx] = hwr[b * Hz + idx];
      __syncthreads();
      {
        const int t = tid >> 3;  // 128 tasks x 8 lanes: score dot
        float acc = idot<32, 8>((const float4*)(encout_g + ((long)(b * Tz) + t) * Hz),
                                (const float4*)hb_s, l8);
        acc += __shfl_xor(acc, 1); acc += __shfl_xor(acc, 2); acc += __shfl_xor(acc, 4);
        if (l8 == 0) sc_s[t] = (inputs[b * Tz + t] != 0) ? acc : -1e30f;
        const int a = tid >> 3;  // 128 tasks x 8 lanes: qh dot
        float qa = idot<32, 8>((const float4*)(W_av + (long)(abase + a) * (2 * Hz) + Hz),
                               (const float4*)hb_s, l8);
        qa += __shfl_xor(qa, 1); qa += __shfl_xor(qa, 2); qa += __shfl_xor(qa, 4);
        if (l8 == 0) qh_s[a] = qa;
      }
      __syncthreads();
      if (tid < 64) {  // softmax over 128 in wave 0
        float s0 = sc_s[tid], s1 = sc_s[64 + tid];
        float m = fmaxf(s0, s1);
#pragma unroll
        for (int off = 32; off; off >>= 1) m = fmaxf(m, __shfl_xor(m, off));
        float e0 = expf(s0 - m), e1 = expf(s1 - m);
        float sum = e0 + e1;
#pragma unroll
        for (int off = 32; off; off >>= 1) sum += __shfl_xor(sum, off);
        e1_s[tid] = e0; e1_s[64 + tid] = e1;
        if (tid == 0) sinv_s = 1.0f / sum;
      }
      __syncthreads();
      {
        const int a = tid >> 3;  // 128 tasks x 8 lanes: context dot over t
        float ctx = idot<4, 8>((const float4*)(pt_g + ((long)(b * Az) + abase + a) * Tz),
                               (const float4*)e1_s, l8);
        ctx += __shfl_xor(ctx, 1); ctx += __shfl_xor(ctx, 2); ctx += __shfl_xor(ctx, 4);
        if (l8 == 0)
          av_g[b * Az + abase + a] = tanhf(ctx * sinv_s + qh_s[a] + b_av[abase + a]);
      }
      if (bid < 4 && tid < 128)  // slice-0 blocks also emit attention weights
        out_aw[(long)s * (Bz * Tz) + bid * Tz + tid] = e1_s[tid] * sinv_s;
      __syncthreads();  // drain av/aw stores before release
      if (tid == 0) st_rel(avseq + bid, (u32)(s + 1));
    }

    // ---- all blocks: wait for av ready (16 slot producers) ----
    poll16(avseq, (u32)(s + 1));

    // ---- P3: logits from register-resident W_cls + block-local argmax ----
    for (int idx = tid; idx < Bz * Az; idx += NTHR)
      at_s[idx >> 9][idx & 511] = av_g[idx];
    __syncthreads();
#pragma unroll
    for (int b = 0; b < 4; ++b) {
      const float4* a4 = (const float4*)&at_s[b][0];
      float acc = 0.f;
#pragma unroll
      for (int k = 0; k < 8; ++k) {
        float4 a = a4[l16 + 16 * k];
        acc += wreg[k].x * a.x + wreg[k].y * a.y + wreg[k].z * a.z + wreg[k].w * a.w;
      }
      acc += __shfl_xor(acc, 1); acc += __shfl_xor(acc, 2);
      acc += __shfl_xor(acc, 4); acc += __shfl_xor(acc, 8);
      if (l16 == 0 && task16 < nrows) {
        acc += bclsr;
        out_pred[((long)s * Bz + b) * Vz + myrow] = acc;
        u32 u = __float_as_uint(acc);
        u = (u & 0x80000000u) ? ~u : (u | 0x80000000u);
        am_s[b][task16] = ((u64)u << 32) | (u64)(0xFFFFFFFFu - (u32)myrow);
      }
    }
    __syncthreads();
    if (tid < 256) {
      int b2 = tid >> 6, l = tid & 63;
      u64 best = (l < nrows) ? am_s[b2][l] : 0ull;
      for (int off = 32; off; off >>= 1) {
        u64 o = __shfl_xor(best, off);
        best = o > best ? o : best;
      }
      if (l == 0) amax_g[bid * 4 + b2] = best;
    }
    __syncthreads();
    if (tid == 0) st_rel(amseq + bid, (u32)(s + 1));  // partials published
  }
}

extern "C" void kernel_launch(void* const* d_in, const int* in_sizes, int n_in,
                              void* d_out, int out_size, void* d_ws, size_t ws_size,
                              hipStream_t stream) {
  const int* inputs = (const int*)d_in[0];
  const float* enc_emb = (const float*)d_in[1];
  const float* enc_Wih = (const float*)d_in[2];
  const float* enc_Whh = (const float*)d_in[3];
  const float* enc_bih = (const float*)d_in[4];
  const float* enc_bhh = (const float*)d_in[5];
  const float* dec_emb = (const float*)d_in[6];
  const float* dec_Wih = (const float*)d_in[7];
  const float* dec_Whh = (const float*)d_in[8];
  const float* dec_bih = (const float*)d_in[9];
  const float* dec_bhh = (const float*)d_in[10];
  const float* W_av = (const float*)d_in[11];
  const float* b_av = (const float*)d_in[12];
  const float* W_cls = (const float*)d_in[13];
  const float* b_cls = (const float*)d_in[14];

  // zero ctrl + seq arrays + h (both buffers) + attn_vec; 0xFF argmax partials
  // so step-0 ids decode to 0 (amseq init 0 => step-0 poll target 0 passes).
  hipMemsetAsync(d_ws, 0, 57344, stream);
  hipMemsetAsync((char*)d_ws + 57344, 0xFF, 8192, stream);

  seq2seq_kernel<<<dim3(NBLK), dim3(NTHR), 0, stream>>>(
      inputs, enc_emb, enc_Wih, enc_Whh, enc_bih, enc_bhh,
      dec_emb, dec_Wih, dec_Whh, dec_bih, dec_bhh,
      W_av, b_av, W_cls, b_cls,
      (float*)d_out, (char*)d_ws);
}